// Round 1
// baseline (4062.230 us; speedup 1.0000x reference)
//
#include <hip/hip_runtime.h>
#include <hip/hip_bf16.h>
#include <hip/hip_cooperative_groups.h>
#include <stdint.h>

namespace cg = cooperative_groups;

// Shapes (fixed by the problem)
#define BB 32
#define TT 128
#define VV 16000
#define EE 512
#define HH 1024
#define FF 2048

typedef __attribute__((ext_vector_type(8))) short short8;   // 8 bf16 = 4 VGPRs (MFMA A/B frag)
typedef __attribute__((ext_vector_type(4))) float floatx4;  // MFMA C/D frag

static __device__ __forceinline__ float bf2f(ushort u) {
    union { unsigned int i; float f; } v; v.i = ((unsigned int)u) << 16; return v.f;
}
static __device__ __forceinline__ ushort f2bf(float f) {
    union { float f; unsigned int i; } v; v.f = f;
    unsigned int x = v.i;
    return (ushort)((x + 0x7fffu + ((x >> 16) & 1u)) >> 16);   // RNE
}
static __device__ __forceinline__ float sigf(float x) {
    return 1.0f / (1.0f + __expf(-x));
}

// read 8 consecutive elements as a bf16 MFMA fragment, from bf16 or fp32 storage
static __device__ __forceinline__ short8 ld8(const char* p, int f32) {
    if (f32) {
        const float4 a = *(const float4*)p;
        const float4 b = *(const float4*)(p + 16);
        short8 r;
        r[0] = (short)f2bf(a.x); r[1] = (short)f2bf(a.y);
        r[2] = (short)f2bf(a.z); r[3] = (short)f2bf(a.w);
        r[4] = (short)f2bf(b.x); r[5] = (short)f2bf(b.y);
        r[6] = (short)f2bf(b.z); r[7] = (short)f2bf(b.w);
        return r;
    }
    return *(const short8*)p;
}
static __device__ __forceinline__ float ldsc(const char* b, int i, int f32) {
    return f32 ? ((const float*)b)[i] : bf2f(((const ushort*)b)[i]);
}

// ---------------------------------------------------------------------------
// Detect storage dtype of float inputs by sampling fc_W as ushorts.
__global__ void detect_kernel(const ushort* __restrict__ w, int* __restrict__ flag) {
    if (threadIdx.x == 0 && blockIdx.x == 0) {
        int cnt = 0;
        for (int i = 0; i < 512; i += 2) {
            ushort u = w[i];
            float x = bf2f(u);
            float ax = x < 0.f ? -x : x;
            if (u == 0u || u == 0x8000u || ax > 100.f) cnt++;
        }
        *flag = (cnt >= 8) ? 1 : 0;
    }
}

// generic elementwise convert (bf16|fp32 -> bf16), used once for W_hh
__global__ void conv_kernel(const char* __restrict__ in, ushort* __restrict__ out,
                            int n, const int* __restrict__ flagp) {
    int i = blockIdx.x * 256 + threadIdx.x;
    if (i >= n) return;
    int fl = *flagp;
    out[i] = fl ? f2bf(((const float*)in)[i]) : ((const ushort*)in)[i];
}

// pooled[b*F+f] = mean over 7x7 of features (bf16 out)
__global__ void pool_kernel(const char* __restrict__ feats, ushort* __restrict__ pooled,
                            const int* __restrict__ flagp) {
    int p = blockIdx.x * 256 + threadIdx.x;        // 0 .. B*F-1 = 65535
    int fl = *flagp;
    float s = 0.f;
    if (fl) {
        const float* src = (const float*)feats + (size_t)p * 49;
        #pragma unroll
        for (int i = 0; i < 49; i++) s += src[i];
    } else {
        const ushort* src = (const ushort*)feats + (size_t)p * 49;
        #pragma unroll
        for (int i = 0; i < 49; i++) s += bf2f(src[i]);
    }
    pooled[p] = f2bf(s * (1.0f / 49.0f));
}

// initb[:, :1024] -> contiguous h0 ping-pong slot 0
__global__ void h0prep_kernel(const ushort* __restrict__ initb, ushort* __restrict__ hb) {
    int i = blockIdx.x * 256 + threadIdx.x;        // 0..32767
    int b = i >> 10, j = i & 1023;
    hb[i] = initb[b * 2048 + j];
}

// ridx[row] = embedding row for logical GEMM row.  TRANSPOSED layout: row = t*B + b
// so that gx is stored [t][b][4096] and each LSTM step reads one contiguous slice.
__global__ void ridx_kernel(const int* __restrict__ reports, int* __restrict__ ridx) {
    int row = blockIdx.x * 256 + threadIdx.x;      // 0..4095
    int b = row & 31, t = row >> 5;
    ridx[row] = (t == 0) ? 1 : reports[b * TT + t - 1];
}

// ---------------------------------------------------------------------------
// Generic GEMM: C(M,N) = A(M,K) @ Bm(N,K)^T + bias1 [+ bias2].
// swapxy=1: bm=blockIdx.x, bn=blockIdx.y  (consecutive blocks share the B-strip
// -> B pulled from HBM once; A (small) stays L2/L3-hot)
__global__ __launch_bounds__(256) void gemm_bf16(
    const char* __restrict__ A, const char* __restrict__ Bm,
    const int* __restrict__ ridx,
    const char* __restrict__ bias1, const char* __restrict__ bias2,
    char* __restrict__ C, int M, int N, int K,
    const int* __restrict__ flagp, int aext, int bext, int oext, int swapxy)
{
    __shared__ ushort As[128 * 32];
    __shared__ ushort Bs[128 * 32];
    const int fl = *flagp;
    const int af32 = aext & fl, bf32 = bext & fl;
    const size_t eA = af32 ? 4 : 2, eB = bf32 ? 4 : 2;

    const int tid  = threadIdx.x;
    const int wave = tid >> 6, lane = tid & 63;
    const int ln = lane & 15, quad = lane >> 4;
    const int wm = wave & 1, wn = wave >> 1;
    const int bm = swapxy ? blockIdx.x : blockIdx.y;
    const int bn = swapxy ? blockIdx.y : blockIdx.x;

    floatx4 acc[4][4] = {};

    const int c0 = tid, c1 = 256 + tid;
    int lr0 = bm * 128 + (c0 >> 2); if (lr0 >= M) lr0 = M - 1;
    int lr1 = bm * 128 + (c1 >> 2); if (lr1 >= M) lr1 = M - 1;
    const int rA0 = ridx ? ridx[lr0] : lr0;
    const int rA1 = ridx ? ridx[lr1] : lr1;
    const int rB0 = bn * 128 + (c0 >> 2);
    const int rB1 = bn * 128 + (c1 >> 2);
    const char* gA0 = A  + ((size_t)rA0 * K + (c0 & 3) * 8) * eA;
    const char* gA1 = A  + ((size_t)rA1 * K + (c1 & 3) * 8) * eA;
    const char* gB0 = Bm + ((size_t)rB0 * K + (c0 & 3) * 8) * eB;
    const char* gB1 = Bm + ((size_t)rB1 * K + (c1 & 3) * 8) * eB;

    for (int k0 = 0; k0 < K; k0 += 32) {
        short8 va0 = ld8(gA0 + (size_t)k0 * eA, af32);
        short8 va1 = ld8(gA1 + (size_t)k0 * eA, af32);
        short8 vb0 = ld8(gB0 + (size_t)k0 * eB, bf32);
        short8 vb1 = ld8(gB1 + (size_t)k0 * eB, bf32);
        __syncthreads();
        *(short8*)(As + c0 * 8) = va0;
        *(short8*)(As + c1 * 8) = va1;
        *(short8*)(Bs + c0 * 8) = vb0;
        *(short8*)(Bs + c1 * 8) = vb1;
        __syncthreads();

        short8 af[4], bfg[4];
        #pragma unroll
        for (int i = 0; i < 4; i++)
            af[i] = *(const short8*)(As + (wm * 64 + i * 16 + ln) * 32 + quad * 8);
        #pragma unroll
        for (int i = 0; i < 4; i++)
            bfg[i] = *(const short8*)(Bs + (wn * 64 + i * 16 + ln) * 32 + quad * 8);
        #pragma unroll
        for (int i = 0; i < 4; i++)
            #pragma unroll
            for (int j = 0; j < 4; j++)
                acc[i][j] = __builtin_amdgcn_mfma_f32_16x16x32_bf16(af[i], bfg[j], acc[i][j], 0, 0, 0);
    }

    const int of32 = oext & fl;
    const int col_base = bn * 128 + wn * 64;
    const int row_base = bm * 128 + wm * 64;
    #pragma unroll
    for (int j = 0; j < 4; j++) {
        const int col = col_base + j * 16 + ln;
        float bb = ldsc(bias1, col, fl);
        if (bias2) bb += ldsc(bias2, col, fl);
        #pragma unroll
        for (int i = 0; i < 4; i++) {
            const int row0 = row_base + i * 16 + quad * 4;
            #pragma unroll
            for (int r = 0; r < 4; r++) {
                const int row = row0 + r;
                if (row < M) {
                    float v = acc[i][j][r] + bb;
                    if (of32) ((float*)C)[(size_t)row * N + col] = v;
                    else      ((ushort*)C)[(size_t)row * N + col] = f2bf(v);
                }
            }
        }
    }
}

// ---------------------------------------------------------------------------
// Persistent LSTM: all 128 steps in ONE cooperative kernel.
// 64 blocks x 256 threads (4 waves = 4 gates), 1 block/CU.
// Per wave: its 16 W_hh rows (16 cols x K=1024 bf16 = 32KB) live in 128 VGPRs
// for the whole kernel.  c lives in 2 registers/thread.  h ping-pongs through
// a contiguous 64KB global buffer; grid.sync() per step.
__global__ __launch_bounds__(256, 1) void lstm_kernel(
    const ushort* __restrict__ Whhb,   // [4096][1024] bf16
    const ushort* __restrict__ gx,     // [t*32+b][4096] bf16 (transposed layout)
    const ushort* __restrict__ initb,  // [32][2048] bf16 (h0 | c0)
    ushort* __restrict__ hbuf,         // 2 x [32][1024] bf16 ping-pong (slot0 = h0)
    ushort* __restrict__ hs)           // [b][t][1024] bf16
{
    __shared__ float gbuf[4][32][16];
    const int jt = blockIdx.x;                 // 0..63 -> hidden cols jt*16..+15
    const int tid = threadIdx.x;
    const int w = tid >> 6, lane = tid & 63;   // w = gate (i,f,g,o)
    const int ln = lane & 15, quad = lane >> 4;
    const int n = w * 1024 + jt * 16 + ln;     // gate-matrix column

    // W_hh fragments -> registers (static indices only; 32 x short8 = 128 VGPR)
    short8 wf[32];
    {
        const ushort* wb = Whhb + (size_t)n * HH + quad * 8;
        #pragma unroll
        for (int kc = 0; kc < 32; kc++)
            wf[kc] = *(const short8*)(wb + kc * 32);
    }

    // c in registers: thread tid owns cells p=tid and p=tid+256 (b = p>>4, jl = p&15)
    const int b0 = tid >> 4, jl = tid & 15;
    const int ccol = jt * 16 + jl;
    float creg0 = bf2f(initb[(size_t)b0 * 2048 + 1024 + ccol]);
    float creg1 = bf2f(initb[(size_t)(b0 + 16) * 2048 + 1024 + ccol]);

    cg::grid_group grid = cg::this_grid();

    #pragma unroll 1
    for (int t = 0; t < TT; t++) {
        const ushort* hp = hbuf + (size_t)(t & 1) * BB * HH;
        ushort* hnx      = hbuf + (size_t)((t + 1) & 1) * BB * HH;

        // prefetch this step's gx scalars (contiguous 256KB slice, latency hides
        // under the MFMA loop)
        ushort gxr[8];
        {
            const ushort* gp = gx + (size_t)t * BB * 4096 + n;
            #pragma unroll
            for (int r = 0; r < 4; r++) {
                gxr[r]     = gp[(size_t)(quad * 4 + r) * 4096];
                gxr[4 + r] = gp[(size_t)(16 + quad * 4 + r) * 4096];
            }
        }

        // h @ W_hh^T : two M-tiles (batches 0-15, 16-31), even/odd K chains
        const ushort* a0p = hp + (size_t)ln * HH + quad * 8;
        const ushort* a1p = hp + (size_t)(16 + ln) * HH + quad * 8;
        floatx4 acc0a = {}, acc0b = {}, acc1a = {}, acc1b = {};
        #pragma unroll
        for (int kc = 0; kc < 32; kc += 2) {
            short8 a0 = *(const short8*)(a0p + kc * 32);
            short8 a1 = *(const short8*)(a1p + kc * 32);
            short8 a2 = *(const short8*)(a0p + kc * 32 + 32);
            short8 a3 = *(const short8*)(a1p + kc * 32 + 32);
            acc0a = __builtin_amdgcn_mfma_f32_16x16x32_bf16(a0, wf[kc],     acc0a, 0, 0, 0);
            acc1a = __builtin_amdgcn_mfma_f32_16x16x32_bf16(a1, wf[kc],     acc1a, 0, 0, 0);
            acc0b = __builtin_amdgcn_mfma_f32_16x16x32_bf16(a2, wf[kc + 1], acc0b, 0, 0, 0);
            acc1b = __builtin_amdgcn_mfma_f32_16x16x32_bf16(a3, wf[kc + 1], acc1b, 0, 0, 0);
        }

        // gates -> LDS (C/D layout: row = quad*4+r, col = ln)
        #pragma unroll
        for (int r = 0; r < 4; r++) {
            gbuf[w][quad * 4 + r][ln]      = acc0a[r] + acc0b[r] + bf2f(gxr[r]);
            gbuf[w][16 + quad * 4 + r][ln] = acc1a[r] + acc1b[r] + bf2f(gxr[4 + r]);
        }
        __syncthreads();

        // cell update: thread owns (b0, jl) and (b0+16, jl)
        {
            const float iv = gbuf[0][b0][jl], fv = gbuf[1][b0][jl];
            const float gv = gbuf[2][b0][jl], ov = gbuf[3][b0][jl];
            creg0 = sigf(fv) * creg0 + sigf(iv) * tanhf(gv);
            ushort hv = f2bf(sigf(ov) * tanhf(creg0));
            hnx[(size_t)b0 * HH + ccol] = hv;
            hs[((size_t)b0 * TT + t) * HH + ccol] = hv;
        }
        {
            const int b1 = b0 + 16;
            const float iv = gbuf[0][b1][jl], fv = gbuf[1][b1][jl];
            const float gv = gbuf[2][b1][jl], ov = gbuf[3][b1][jl];
            creg1 = sigf(fv) * creg1 + sigf(iv) * tanhf(gv);
            ushort hv = f2bf(sigf(ov) * tanhf(creg1));
            hnx[(size_t)b1 * HH + ccol] = hv;
            hs[((size_t)b1 * TT + t) * HH + ccol] = hv;
        }

        __threadfence();
        grid.sync();
    }
}

// ---------------------------------------------------------------------------
extern "C" void kernel_launch(void* const* d_in, const int* in_sizes, int n_in,
                              void* d_out, int out_size, void* d_ws, size_t ws_size,
                              hipStream_t stream) {
    const char* feats   = (const char*)d_in[0];
    const int*  reports = (const int*) d_in[1];
    const char* fcW     = (const char*)d_in[2];
    const char* fcb     = (const char*)d_in[3];
    const char* emb     = (const char*)d_in[4];
    const char* Wih     = (const char*)d_in[5];
    const char* Whh     = (const char*)d_in[6];
    const char* bih     = (const char*)d_in[7];
    const char* bhh     = (const char*)d_in[8];
    const char* Wv      = (const char*)d_in[9];
    const char* bv      = (const char*)d_in[10];

    // workspace layout (~48.5 MB total), big-first, 16B-aligned
    char* p = (char*)d_ws;
    ushort* gx     = (ushort*)p; p += (size_t)BB * TT * 4096 * 2;     // 32 MB
    ushort* hs     = (ushort*)p; p += (size_t)BB * TT * HH * 2;       // 8 MB
    ushort* Whhb   = (ushort*)p; p += (size_t)4096 * HH * 2;          // 8 MB
    ushort* pooled = (ushort*)p; p += (size_t)BB * FF * 2;            // 128 KB
    ushort* initb  = (ushort*)p; p += (size_t)BB * 2048 * 2;          // 128 KB
    ushort* hbuf   = (ushort*)p; p += (size_t)2 * BB * HH * 2;        // 128 KB
    int*    ridx   = (int*)   p; p += (size_t)BB * TT * 4;            // 16 KB
    int*    flag   = (int*)   p; p += 16;

    detect_kernel<<<1, 64, 0, stream>>>((const ushort*)fcW, flag);
    conv_kernel  <<<16384, 256, 0, stream>>>(Whh, Whhb, 4096 * HH, flag);
    pool_kernel  <<<256, 256, 0, stream>>>(feats, pooled, flag);
    ridx_kernel  <<<16,  256, 0, stream>>>(reports, ridx);

    gemm_bf16<<<dim3(16, 1), 256, 0, stream>>>((const char*)pooled, fcW, nullptr,
                                               fcb, nullptr, (char*)initb,
                                               32, 2048, 2048, flag, 0, 1, 0, 0);
    h0prep_kernel<<<128, 256, 0, stream>>>(initb, hbuf);
    // gates_x = emb[in_idx] @ W_ih^T + (b_ih + b_hh), rows = t*B + b (transposed)
    gemm_bf16<<<dim3(32, 32), 256, 0, stream>>>(emb, Wih, ridx, bih, bhh,
                                                (char*)gx, BB * TT, 4096, EE,
                                                flag, 1, 1, 0, 1);

    {
        const ushort* a0 = Whhb; const ushort* a1 = gx; const ushort* a2 = initb;
        ushort* a3 = hbuf; ushort* a4 = hs;
        void* kargs[] = { (void*)&a0, (void*)&a1, (void*)&a2, (void*)&a3, (void*)&a4 };
        hipLaunchCooperativeKernel(lstm_kernel, dim3(64), dim3(256), kargs, 0, stream);
    }

    // final: seq_out = hs @ Wv^T + bv  (swapxy: consecutive blocks share Wv strip)
    gemm_bf16<<<dim3(32, 125), 256, 0, stream>>>((const char*)hs, Wv, nullptr,
                                                 bv, nullptr, (char*)d_out,
                                                 BB * TT, VV, HH, flag, 0, 1, 1, 1);
}

// Round 2
// 2229.218 us; speedup vs baseline: 1.8223x; 1.8223x over previous
//
#include <hip/hip_runtime.h>
#include <hip/hip_bf16.h>
#include <stdint.h>

// Shapes (fixed by the problem)
#define BB 32
#define TT 128
#define VV 16000
#define EE 512
#define HH 1024
#define FF 2048
#define NBLK 64   // lstm grid size

typedef __attribute__((ext_vector_type(8))) short short8;   // 8 bf16 = 4 VGPRs (MFMA A/B frag)
typedef __attribute__((ext_vector_type(4))) float floatx4;  // MFMA C/D frag

static __device__ __forceinline__ float bf2f(ushort u) {
    union { unsigned int i; float f; } v; v.i = ((unsigned int)u) << 16; return v.f;
}
static __device__ __forceinline__ ushort f2bf(float f) {
    union { float f; unsigned int i; } v; v.f = f;
    unsigned int x = v.i;
    return (ushort)((x + 0x7fffu + ((x >> 16) & 1u)) >> 16);   // RNE
}
static __device__ __forceinline__ float sigf(float x) {
    return 1.0f / (1.0f + __expf(-x));
}

// read 8 consecutive elements as a bf16 MFMA fragment, from bf16 or fp32 storage
static __device__ __forceinline__ short8 ld8(const char* p, int f32) {
    if (f32) {
        const float4 a = *(const float4*)p;
        const float4 b = *(const float4*)(p + 16);
        short8 r;
        r[0] = (short)f2bf(a.x); r[1] = (short)f2bf(a.y);
        r[2] = (short)f2bf(a.z); r[3] = (short)f2bf(a.w);
        r[4] = (short)f2bf(b.x); r[5] = (short)f2bf(b.y);
        r[6] = (short)f2bf(b.z); r[7] = (short)f2bf(b.w);
        return r;
    }
    return *(const short8*)p;
}
static __device__ __forceinline__ float ldsc(const char* b, int i, int f32) {
    return f32 ? ((const float*)b)[i] : bf2f(((const ushort*)b)[i]);
}

// ---------------------------------------------------------------------------
// Detect storage dtype of float inputs by sampling fc_W as ushorts.
__global__ void detect_kernel(const ushort* __restrict__ w, int* __restrict__ flag) {
    if (threadIdx.x == 0 && blockIdx.x == 0) {
        int cnt = 0;
        for (int i = 0; i < 512; i += 2) {
            ushort u = w[i];
            float x = bf2f(u);
            float ax = x < 0.f ? -x : x;
            if (u == 0u || u == 0x8000u || ax > 100.f) cnt++;
        }
        *flag = (cnt >= 8) ? 1 : 0;
    }
}

// generic elementwise convert (bf16|fp32 -> bf16), used once for W_hh
__global__ void conv_kernel(const char* __restrict__ in, ushort* __restrict__ out,
                            int n, const int* __restrict__ flagp) {
    int i = blockIdx.x * 256 + threadIdx.x;
    if (i >= n) return;
    int fl = *flagp;
    out[i] = fl ? f2bf(((const float*)in)[i]) : ((const ushort*)in)[i];
}

// pooled[b*F+f] = mean over 7x7 of features (bf16 out)
__global__ void pool_kernel(const char* __restrict__ feats, ushort* __restrict__ pooled,
                            const int* __restrict__ flagp) {
    int p = blockIdx.x * 256 + threadIdx.x;        // 0 .. B*F-1 = 65535
    int fl = *flagp;
    float s = 0.f;
    if (fl) {
        const float* src = (const float*)feats + (size_t)p * 49;
        #pragma unroll
        for (int i = 0; i < 49; i++) s += src[i];
    } else {
        const ushort* src = (const ushort*)feats + (size_t)p * 49;
        #pragma unroll
        for (int i = 0; i < 49; i++) s += bf2f(src[i]);
    }
    pooled[p] = f2bf(s * (1.0f / 49.0f));
}

// initb[:, :1024] -> contiguous h0 ping-pong slot 0; also zero the barrier counter
__global__ void h0prep_kernel(const ushort* __restrict__ initb, ushort* __restrict__ hb,
                              unsigned int* __restrict__ barcnt) {
    int i = blockIdx.x * 256 + threadIdx.x;        // 0..32767
    int b = i >> 10, j = i & 1023;
    hb[i] = initb[b * 2048 + j];
    if (i == 0)
        __hip_atomic_store(barcnt, 0u, __ATOMIC_RELAXED, __HIP_MEMORY_SCOPE_AGENT);
}

// ridx[row] = embedding row for logical GEMM row.  TRANSPOSED layout: row = t*B + b
// so that gx is stored [t][b][4096] and each LSTM step reads one contiguous slice.
__global__ void ridx_kernel(const int* __restrict__ reports, int* __restrict__ ridx) {
    int row = blockIdx.x * 256 + threadIdx.x;      // 0..4095
    int b = row & 31, t = row >> 5;
    ridx[row] = (t == 0) ? 1 : reports[b * TT + t - 1];
}

// ---------------------------------------------------------------------------
// Generic GEMM: C(M,N) = A(M,K) @ Bm(N,K)^T + bias1 [+ bias2].
__global__ __launch_bounds__(256) void gemm_bf16(
    const char* __restrict__ A, const char* __restrict__ Bm,
    const int* __restrict__ ridx,
    const char* __restrict__ bias1, const char* __restrict__ bias2,
    char* __restrict__ C, int M, int N, int K,
    const int* __restrict__ flagp, int aext, int bext, int oext, int swapxy)
{
    __shared__ ushort As[128 * 32];
    __shared__ ushort Bs[128 * 32];
    const int fl = *flagp;
    const int af32 = aext & fl, bf32 = bext & fl;
    const size_t eA = af32 ? 4 : 2, eB = bf32 ? 4 : 2;

    const int tid  = threadIdx.x;
    const int wave = tid >> 6, lane = tid & 63;
    const int ln = lane & 15, quad = lane >> 4;
    const int wm = wave & 1, wn = wave >> 1;
    const int bm = swapxy ? blockIdx.x : blockIdx.y;
    const int bn = swapxy ? blockIdx.y : blockIdx.x;

    floatx4 acc[4][4] = {};

    const int c0 = tid, c1 = 256 + tid;
    int lr0 = bm * 128 + (c0 >> 2); if (lr0 >= M) lr0 = M - 1;
    int lr1 = bm * 128 + (c1 >> 2); if (lr1 >= M) lr1 = M - 1;
    const int rA0 = ridx ? ridx[lr0] : lr0;
    const int rA1 = ridx ? ridx[lr1] : lr1;
    const int rB0 = bn * 128 + (c0 >> 2);
    const int rB1 = bn * 128 + (c1 >> 2);
    const char* gA0 = A  + ((size_t)rA0 * K + (c0 & 3) * 8) * eA;
    const char* gA1 = A  + ((size_t)rA1 * K + (c1 & 3) * 8) * eA;
    const char* gB0 = Bm + ((size_t)rB0 * K + (c0 & 3) * 8) * eB;
    const char* gB1 = Bm + ((size_t)rB1 * K + (c1 & 3) * 8) * eB;

    for (int k0 = 0; k0 < K; k0 += 32) {
        short8 va0 = ld8(gA0 + (size_t)k0 * eA, af32);
        short8 va1 = ld8(gA1 + (size_t)k0 * eA, af32);
        short8 vb0 = ld8(gB0 + (size_t)k0 * eB, bf32);
        short8 vb1 = ld8(gB1 + (size_t)k0 * eB, bf32);
        __syncthreads();
        *(short8*)(As + c0 * 8) = va0;
        *(short8*)(As + c1 * 8) = va1;
        *(short8*)(Bs + c0 * 8) = vb0;
        *(short8*)(Bs + c1 * 8) = vb1;
        __syncthreads();

        short8 af[4], bfg[4];
        #pragma unroll
        for (int i = 0; i < 4; i++)
            af[i] = *(const short8*)(As + (wm * 64 + i * 16 + ln) * 32 + quad * 8);
        #pragma unroll
        for (int i = 0; i < 4; i++)
            bfg[i] = *(const short8*)(Bs + (wn * 64 + i * 16 + ln) * 32 + quad * 8);
        #pragma unroll
        for (int i = 0; i < 4; i++)
            #pragma unroll
            for (int j = 0; j < 4; j++)
                acc[i][j] = __builtin_amdgcn_mfma_f32_16x16x32_bf16(af[i], bfg[j], acc[i][j], 0, 0, 0);
    }

    const int of32 = oext & fl;
    const int col_base = bn * 128 + wn * 64;
    const int row_base = bm * 128 + wm * 64;
    #pragma unroll
    for (int j = 0; j < 4; j++) {
        const int col = col_base + j * 16 + ln;
        float bb = ldsc(bias1, col, fl);
        if (bias2) bb += ldsc(bias2, col, fl);
        #pragma unroll
        for (int i = 0; i < 4; i++) {
            const int row0 = row_base + i * 16 + quad * 4;
            #pragma unroll
            for (int r = 0; r < 4; r++) {
                const int row = row0 + r;
                if (row < M) {
                    float v = acc[i][j][r] + bb;
                    if (of32) ((float*)C)[(size_t)row * N + col] = v;
                    else      ((ushort*)C)[(size_t)row * N + col] = f2bf(v);
                }
            }
        }
    }
}

// ---------------------------------------------------------------------------
// Persistent LSTM, v2.  64 blocks x 512 threads (8 waves, 2/SIMD).
// Block jb owns hidden cols [jb*16, jb*16+16) for ALL 4 gates -> cell update is
// block-local.  Wave w = (gate s = w>>1, K-half q = w&1); its W_hh fragment
// (16 cols x 512 k = 16 x short8 = 64 VGPR) is register-resident for the whole
// kernel.  All cross-block traffic (h, hs) moves through the coherence point
// via agent-scope atomics (sc0/sc1) -> NO cache-invalidating fences needed, so
// W stays in registers and gx stays L2-clean.  Barrier = monotonic counter:
// release-fence + relaxed fetch_add; consumers spin on relaxed agent load.
__global__ __launch_bounds__(512, 2) void lstm_kernel(
    const ushort* __restrict__ Whhb,   // [4096][1024] bf16
    const ushort* __restrict__ gx,     // [t*32+b][4096] bf16
    const ushort* __restrict__ initb,  // [32][2048] bf16 (h0 | c0)
    ushort* __restrict__ hbuf,         // 2 x [32][1024] bf16 ping-pong (slot0 = h0)
    ushort* __restrict__ hs,           // [b][t][1024] bf16
    unsigned int* __restrict__ barcnt)
{
    __shared__ ushort hsm[32 * 1024];          // 64 KB, rows XOR-swizzled (G4 recipe)
    __shared__ float pbuf[8][32][17];          // partial gates, padded vs bank conflicts

    const int jb = blockIdx.x;                 // hidden-col block
    const int tid = threadIdx.x;
    const int w = tid >> 6;                    // wave 0..7
    const int lane = tid & 63;
    const int ln = lane & 15, quad = lane >> 4;
    const int s = w >> 1, q = w & 1;           // gate, K-half

    // W_hh fragments -> registers (64 VGPR): Whh[s*1024 + jb*16 + ln][q*512 + kc*32 + quad*8]
    short8 wf[16];
    {
        const ushort* wb = Whhb + (size_t)(s * 1024 + jb * 16 + ln) * HH + q * 512 + quad * 8;
        #pragma unroll
        for (int kc = 0; kc < 16; kc++)
            wf[kc] = *(const short8*)(wb + kc * 32);
    }

    // cell ownership: thread tid -> (batch cb, hidden col hcol); c in a register
    const int cb = tid >> 4, hc = tid & 15;
    const int hcol = jb * 16 + hc;
    float creg = bf2f(initb[(size_t)cb * 2048 + 1024 + hcol]);

    #pragma unroll 1
    for (int t = 0; t < TT; t++) {
        // gx prefetch (independent of h -> hides under barrier wait)
        float gxv[4];
        {
            const ushort* gp = gx + ((size_t)t * BB + cb) * 4096 + hcol;
            #pragma unroll
            for (int g = 0; g < 4; g++) gxv[g] = bf2f(gp[g * 1024]);
        }

        // wait until all 64 blocks finished step t-1
        if (t > 0) {
            if (tid == 0) {
                const unsigned target = (unsigned)(NBLK * t);
                while (__hip_atomic_load(barcnt, __ATOMIC_RELAXED,
                                         __HIP_MEMORY_SCOPE_AGENT) < target)
                    __builtin_amdgcn_s_sleep(1);
            }
            __syncthreads();
            asm volatile("" ::: "memory");     // no hoisting h-loads above the spin
        }

        // cooperative h_t -> LDS via coherent (agent) loads; XOR-swizzle rows
        {
            const ushort* hp = hbuf + (size_t)(t & 1) * BB * HH;
            unsigned long long v[16];
            #pragma unroll
            for (int j = 0; j < 16; j++) {
                const int c = tid + 512 * j;                    // 8B chunk id
                v[j] = __hip_atomic_load((const unsigned long long*)hp + c,
                                         __ATOMIC_RELAXED, __HIP_MEMORY_SCOPE_AGENT);
            }
            #pragma unroll
            for (int j = 0; j < 16; j++) {
                const int c = tid + 512 * j;
                const int row = c >> 8;                         // 2048 B per row
                const int inb = (c & 255) * 8;
                *(unsigned long long*)((char*)hsm + row * 2048 + (inb ^ ((row & 7) << 4))) = v[j];
            }
        }
        __syncthreads();

        // partial gates: (gate s, K-half q) over 32 batches x 16 cols
        floatx4 acc0 = {}, acc1 = {};
        {
            const char* base0 = (const char*)hsm + ln * 2048;
            const char* base1 = (const char*)hsm + (16 + ln) * 2048;
            const int x0 = (ln & 7) << 4, x1 = ((16 + ln) & 7) << 4;
            #pragma unroll
            for (int kc = 0; kc < 16; kc++) {
                const int inb = (q * 512 + kc * 32 + quad * 8) * 2;
                short8 a0 = *(const short8*)(base0 + (inb ^ x0));
                short8 a1 = *(const short8*)(base1 + (inb ^ x1));
                acc0 = __builtin_amdgcn_mfma_f32_16x16x32_bf16(a0, wf[kc], acc0, 0, 0, 0);
                acc1 = __builtin_amdgcn_mfma_f32_16x16x32_bf16(a1, wf[kc], acc1, 0, 0, 0);
            }
        }
        #pragma unroll
        for (int r = 0; r < 4; r++) {
            pbuf[w][quad * 4 + r][ln]      = acc0[r];
            pbuf[w][16 + quad * 4 + r][ln] = acc1[r];
        }
        __syncthreads();

        // cell update: thread owns (cb, hcol)
        {
            float gv[4];
            #pragma unroll
            for (int g = 0; g < 4; g++)
                gv[g] = pbuf[2 * g][cb][hc] + pbuf[2 * g + 1][cb][hc] + gxv[g];
            creg = sigf(gv[1]) * creg + sigf(gv[0]) * tanhf(gv[2]);
            const float hn = sigf(gv[3]) * tanhf(creg);
            unsigned hv = (unsigned)f2bf(hn);
            unsigned up = (unsigned)__shfl_down((int)hv, 1);
            if ((hc & 1) == 0) {                               // paired u32 coherent stores
                const unsigned pk = hv | (up << 16);
                ushort* hnx = hbuf + (size_t)((t + 1) & 1) * BB * HH;
                __hip_atomic_store((unsigned*)(hnx + (size_t)cb * HH + hcol), pk,
                                   __ATOMIC_RELAXED, __HIP_MEMORY_SCOPE_AGENT);
                __hip_atomic_store((unsigned*)(hs + ((size_t)cb * TT + t) * HH + hcol), pk,
                                   __ATOMIC_RELAXED, __HIP_MEMORY_SCOPE_AGENT);
            }
        }

        // release (drain this wave's coherent stores; nothing dirty in L2 -> cheap),
        // then arrive
        __builtin_amdgcn_fence(__ATOMIC_RELEASE, "agent");
        __syncthreads();
        if (tid == 0)
            __hip_atomic_fetch_add(barcnt, 1u, __ATOMIC_RELAXED, __HIP_MEMORY_SCOPE_AGENT);
    }
}

// ---------------------------------------------------------------------------
extern "C" void kernel_launch(void* const* d_in, const int* in_sizes, int n_in,
                              void* d_out, int out_size, void* d_ws, size_t ws_size,
                              hipStream_t stream) {
    const char* feats   = (const char*)d_in[0];
    const int*  reports = (const int*) d_in[1];
    const char* fcW     = (const char*)d_in[2];
    const char* fcb     = (const char*)d_in[3];
    const char* emb     = (const char*)d_in[4];
    const char* Wih     = (const char*)d_in[5];
    const char* Whh     = (const char*)d_in[6];
    const char* bih     = (const char*)d_in[7];
    const char* bhh     = (const char*)d_in[8];
    const char* Wv      = (const char*)d_in[9];
    const char* bv      = (const char*)d_in[10];

    // workspace layout (~48.5 MB total), big-first, 16B-aligned
    char* p = (char*)d_ws;
    ushort* gx     = (ushort*)p; p += (size_t)BB * TT * 4096 * 2;     // 32 MB
    ushort* hs     = (ushort*)p; p += (size_t)BB * TT * HH * 2;       // 8 MB
    ushort* Whhb   = (ushort*)p; p += (size_t)4096 * HH * 2;          // 8 MB
    ushort* pooled = (ushort*)p; p += (size_t)BB * FF * 2;            // 128 KB
    ushort* initb  = (ushort*)p; p += (size_t)BB * 2048 * 2;          // 128 KB
    ushort* hbuf   = (ushort*)p; p += (size_t)2 * BB * HH * 2;        // 128 KB
    int*    ridx   = (int*)   p; p += (size_t)BB * TT * 4;            // 16 KB
    int*    flag   = (int*)   p; p += 16;
    unsigned int* barcnt = (unsigned int*)p; p += 16;

    detect_kernel<<<1, 64, 0, stream>>>((const ushort*)fcW, flag);
    conv_kernel  <<<16384, 256, 0, stream>>>(Whh, Whhb, 4096 * HH, flag);
    pool_kernel  <<<256, 256, 0, stream>>>(feats, pooled, flag);
    ridx_kernel  <<<16,  256, 0, stream>>>(reports, ridx);

    gemm_bf16<<<dim3(16, 1), 256, 0, stream>>>((const char*)pooled, fcW, nullptr,
                                               fcb, nullptr, (char*)initb,
                                               32, 2048, 2048, flag, 0, 1, 0, 0);
    h0prep_kernel<<<128, 256, 0, stream>>>(initb, hbuf, barcnt);
    // gates_x = emb[in_idx] @ W_ih^T + (b_ih + b_hh), rows = t*B + b (transposed)
    gemm_bf16<<<dim3(32, 32), 256, 0, stream>>>(emb, Wih, ridx, bih, bhh,
                                                (char*)gx, BB * TT, 4096, EE,
                                                flag, 1, 1, 0, 1);

    {
        const ushort* a0 = Whhb; const ushort* a1 = gx; const ushort* a2 = initb;
        ushort* a3 = hbuf; ushort* a4 = hs; unsigned int* a5 = barcnt;
        void* kargs[] = { (void*)&a0, (void*)&a1, (void*)&a2,
                          (void*)&a3, (void*)&a4, (void*)&a5 };
        hipLaunchCooperativeKernel(lstm_kernel, dim3(NBLK), dim3(512), kargs, 0, stream);
    }

    // final: seq_out = hs @ Wv^T + bv
    gemm_bf16<<<dim3(32, 125), 256, 0, stream>>>((const char*)hs, Wv, nullptr,
                                                 bv, nullptr, (char*)d_out,
                                                 BB * TT, VV, HH, flag, 0, 1, 1, 1);
}

// Round 3
// 2181.067 us; speedup vs baseline: 1.8625x; 1.0221x over previous
//
#include <hip/hip_runtime.h>
#include <hip/hip_bf16.h>
#include <stdint.h>

// Shapes (fixed by the problem)
#define BB 32
#define TT 128
#define VV 16000
#define EE 512
#define HH 1024
#define FF 2048
#define NBLK 64   // lstm grid size

typedef __attribute__((ext_vector_type(8))) short short8;   // 8 bf16 = 4 VGPRs (MFMA A/B frag)
typedef __attribute__((ext_vector_type(4))) float floatx4;  // MFMA C/D frag

static __device__ __forceinline__ float bf2f(ushort u) {
    union { unsigned int i; float f; } v; v.i = ((unsigned int)u) << 16; return v.f;
}
static __device__ __forceinline__ ushort f2bf(float f) {
    union { float f; unsigned int i; } v; v.f = f;
    unsigned int x = v.i;
    return (ushort)((x + 0x7fffu + ((x >> 16) & 1u)) >> 16);   // RNE
}
static __device__ __forceinline__ float sigf(float x) {
    return 1.0f / (1.0f + __expf(-x));
}

// async global->LDS 16B (dest = wave-uniform base + lane*16)
static __device__ __forceinline__ void gload_lds16(const void* g, void* l) {
    __builtin_amdgcn_global_load_lds(
        (const __attribute__((address_space(1))) unsigned int*)g,
        (__attribute__((address_space(3))) unsigned int*)l, 16, 0, 0);
}

// read 8 consecutive elements as a bf16 MFMA fragment, from bf16 or fp32 storage
static __device__ __forceinline__ short8 ld8(const char* p, int f32) {
    if (f32) {
        const float4 a = *(const float4*)p;
        const float4 b = *(const float4*)(p + 16);
        short8 r;
        r[0] = (short)f2bf(a.x); r[1] = (short)f2bf(a.y);
        r[2] = (short)f2bf(a.z); r[3] = (short)f2bf(a.w);
        r[4] = (short)f2bf(b.x); r[5] = (short)f2bf(b.y);
        r[6] = (short)f2bf(b.z); r[7] = (short)f2bf(b.w);
        return r;
    }
    return *(const short8*)p;
}
static __device__ __forceinline__ float ldsc(const char* b, int i, int f32) {
    return f32 ? ((const float*)b)[i] : bf2f(((const ushort*)b)[i]);
}

// ---------------------------------------------------------------------------
// Detect storage dtype of float inputs by sampling fc_W as ushorts.
__global__ void detect_kernel(const ushort* __restrict__ w, int* __restrict__ flag) {
    if (threadIdx.x == 0 && blockIdx.x == 0) {
        int cnt = 0;
        for (int i = 0; i < 512; i += 2) {
            ushort u = w[i];
            float x = bf2f(u);
            float ax = x < 0.f ? -x : x;
            if (u == 0u || u == 0x8000u || ax > 100.f) cnt++;
        }
        *flag = (cnt >= 8) ? 1 : 0;
    }
}

// generic elementwise convert (bf16|fp32 -> bf16)
__global__ void conv_kernel(const char* __restrict__ in, ushort* __restrict__ out,
                            int n, const int* __restrict__ flagp) {
    int i = blockIdx.x * 256 + threadIdx.x;
    if (i >= n) return;
    int fl = *flagp;
    out[i] = fl ? f2bf(((const float*)in)[i]) : ((const ushort*)in)[i];
}

// pooled[b*F+f] = mean over 7x7 of features (bf16 out)
__global__ void pool_kernel(const char* __restrict__ feats, ushort* __restrict__ pooled,
                            const int* __restrict__ flagp) {
    int p = blockIdx.x * 256 + threadIdx.x;        // 0 .. B*F-1 = 65535
    int fl = *flagp;
    float s = 0.f;
    if (fl) {
        const float* src = (const float*)feats + (size_t)p * 49;
        #pragma unroll
        for (int i = 0; i < 49; i++) s += src[i];
    } else {
        const ushort* src = (const ushort*)feats + (size_t)p * 49;
        #pragma unroll
        for (int i = 0; i < 49; i++) s += bf2f(src[i]);
    }
    pooled[p] = f2bf(s * (1.0f / 49.0f));
}

// initb[:, :1024] -> contiguous h0 ping-pong slot 0; also zero the arrival flags
__global__ void h0prep_kernel(const ushort* __restrict__ initb, ushort* __restrict__ hb,
                              unsigned int* __restrict__ flags) {
    int i = blockIdx.x * 256 + threadIdx.x;        // 0..32767
    int b = i >> 10, j = i & 1023;
    hb[i] = initb[b * 2048 + j];
    if (i < NBLK)
        __hip_atomic_store(flags + i, 0u, __ATOMIC_RELAXED, __HIP_MEMORY_SCOPE_AGENT);
}

// ridx[row] = embedding row for logical GEMM row.  TRANSPOSED layout: row = t*B + b
// so that gx is stored [t][b][4096] and each LSTM step reads one contiguous slice.
__global__ void ridx_kernel(const int* __restrict__ reports, int* __restrict__ ridx) {
    int row = blockIdx.x * 256 + threadIdx.x;      // 0..4095
    int b = row & 31, t = row >> 5;
    ridx[row] = (t == 0) ? 1 : reports[b * TT + t - 1];
}

// ---------------------------------------------------------------------------
// Generic GEMM: C(M,N) = A(M,K) @ Bm(N,K)^T + bias1 [+ bias2].
__global__ __launch_bounds__(256) void gemm_bf16(
    const char* __restrict__ A, const char* __restrict__ Bm,
    const int* __restrict__ ridx,
    const char* __restrict__ bias1, const char* __restrict__ bias2,
    char* __restrict__ C, int M, int N, int K,
    const int* __restrict__ flagp, int aext, int bext, int oext, int swapxy)
{
    __shared__ ushort As[128 * 32];
    __shared__ ushort Bs[128 * 32];
    const int fl = *flagp;
    const int af32 = aext & fl, bf32 = bext & fl;
    const size_t eA = af32 ? 4 : 2, eB = bf32 ? 4 : 2;

    const int tid  = threadIdx.x;
    const int wave = tid >> 6, lane = tid & 63;
    const int ln = lane & 15, quad = lane >> 4;
    const int wm = wave & 1, wn = wave >> 1;
    const int bm = swapxy ? blockIdx.x : blockIdx.y;
    const int bn = swapxy ? blockIdx.y : blockIdx.x;

    floatx4 acc[4][4] = {};

    const int c0 = tid, c1 = 256 + tid;
    int lr0 = bm * 128 + (c0 >> 2); if (lr0 >= M) lr0 = M - 1;
    int lr1 = bm * 128 + (c1 >> 2); if (lr1 >= M) lr1 = M - 1;
    const int rA0 = ridx ? ridx[lr0] : lr0;
    const int rA1 = ridx ? ridx[lr1] : lr1;
    const int rB0 = bn * 128 + (c0 >> 2);
    const int rB1 = bn * 128 + (c1 >> 2);
    const char* gA0 = A  + ((size_t)rA0 * K + (c0 & 3) * 8) * eA;
    const char* gA1 = A  + ((size_t)rA1 * K + (c1 & 3) * 8) * eA;
    const char* gB0 = Bm + ((size_t)rB0 * K + (c0 & 3) * 8) * eB;
    const char* gB1 = Bm + ((size_t)rB1 * K + (c1 & 3) * 8) * eB;

    for (int k0 = 0; k0 < K; k0 += 32) {
        short8 va0 = ld8(gA0 + (size_t)k0 * eA, af32);
        short8 va1 = ld8(gA1 + (size_t)k0 * eA, af32);
        short8 vb0 = ld8(gB0 + (size_t)k0 * eB, bf32);
        short8 vb1 = ld8(gB1 + (size_t)k0 * eB, bf32);
        __syncthreads();
        *(short8*)(As + c0 * 8) = va0;
        *(short8*)(As + c1 * 8) = va1;
        *(short8*)(Bs + c0 * 8) = vb0;
        *(short8*)(Bs + c1 * 8) = vb1;
        __syncthreads();

        short8 af[4], bfg[4];
        #pragma unroll
        for (int i = 0; i < 4; i++)
            af[i] = *(const short8*)(As + (wm * 64 + i * 16 + ln) * 32 + quad * 8);
        #pragma unroll
        for (int i = 0; i < 4; i++)
            bfg[i] = *(const short8*)(Bs + (wn * 64 + i * 16 + ln) * 32 + quad * 8);
        #pragma unroll
        for (int i = 0; i < 4; i++)
            #pragma unroll
            for (int j = 0; j < 4; j++)
                acc[i][j] = __builtin_amdgcn_mfma_f32_16x16x32_bf16(af[i], bfg[j], acc[i][j], 0, 0, 0);
    }

    const int of32 = oext & fl;
    const int col_base = bn * 128 + wn * 64;
    const int row_base = bm * 128 + wm * 64;
    #pragma unroll
    for (int j = 0; j < 4; j++) {
        const int col = col_base + j * 16 + ln;
        float bb = ldsc(bias1, col, fl);
        if (bias2) bb += ldsc(bias2, col, fl);
        #pragma unroll
        for (int i = 0; i < 4; i++) {
            const int row0 = row_base + i * 16 + quad * 4;
            #pragma unroll
            for (int r = 0; r < 4; r++) {
                const int row = row0 + r;
                if (row < M) {
                    float v = acc[i][j][r] + bb;
                    if (of32) ((float*)C)[(size_t)row * N + col] = v;
                    else      ((ushort*)C)[(size_t)row * N + col] = f2bf(v);
                }
            }
        }
    }
}

// ---------------------------------------------------------------------------
// Fast all-bf16 GEMM (m97 structure): global_load_lds width-16 staging,
// 128x128 tile, BK=32.  Requires M%128==0, N%128==0, K%32==0, no ridx.
// XCD-chunked bijective swizzle (grid must be a multiple of 8 blocks).
__global__ __launch_bounds__(256) void gemm_bf16_fast(
    const ushort* __restrict__ A, const ushort* __restrict__ Bm,
    const char* __restrict__ bias,
    char* __restrict__ C, int M, int N, int K,
    const int* __restrict__ flagp, int oext, int gx_, int gy_)
{
    __shared__ ushort As[128 * 32];
    __shared__ ushort Bs[128 * 32];
    const int fl = *flagp;

    const int tid  = threadIdx.x;
    const int wave = tid >> 6, lane = tid & 63;
    const int ln = lane & 15, quad = lane >> 4;
    const int wm = wave & 1, wn = wave >> 1;

    // bijective XCD swizzle over the linearized grid (nwg % 8 == 0)
    const int nwg = gx_ * gy_;
    const int L   = blockIdx.y * gx_ + blockIdx.x;
    const int wg  = (L % 8) * (nwg / 8) + L / 8;
    const int bm  = wg % gx_;          // gx_ = M/128 (fast-moving -> shares B-strip)
    const int bn  = wg / gx_;

    floatx4 acc[4][4] = {};

    // staging: thread stages chunks c0 = tid, c1 = 256+tid (16B each);
    // chunk c -> row c>>2, k-chunk c&3; LDS dest = base(c_block)*16 + lane*16
    const int c0 = tid, c1 = 256 + tid;
    const ushort* gA0 = A  + (size_t)(bm * 128 + (c0 >> 2)) * K + (c0 & 3) * 8;
    const ushort* gA1 = A  + (size_t)(bm * 128 + (c1 >> 2)) * K + (c1 & 3) * 8;
    const ushort* gB0 = Bm + (size_t)(bn * 128 + (c0 >> 2)) * K + (c0 & 3) * 8;
    const ushort* gB1 = Bm + (size_t)(bn * 128 + (c1 >> 2)) * K + (c1 & 3) * 8;
    ushort* lA0 = As + (wave * 64) * 8;          // wave-uniform bases
    ushort* lA1 = As + (256 + wave * 64) * 8;
    ushort* lB0 = Bs + (wave * 64) * 8;
    ushort* lB1 = Bs + (256 + wave * 64) * 8;

    for (int k0 = 0; k0 < K; k0 += 32) {
        __syncthreads();                         // prior iter's LDS reads done
        gload_lds16(gA0 + k0, lA0);
        gload_lds16(gA1 + k0, lA1);
        gload_lds16(gB0 + k0, lB0);
        gload_lds16(gB1 + k0, lB1);
        __syncthreads();                         // compiler drains vmcnt before barrier

        short8 af[4], bfg[4];
        #pragma unroll
        for (int i = 0; i < 4; i++)
            af[i] = *(const short8*)(As + (wm * 64 + i * 16 + ln) * 32 + quad * 8);
        #pragma unroll
        for (int i = 0; i < 4; i++)
            bfg[i] = *(const short8*)(Bs + (wn * 64 + i * 16 + ln) * 32 + quad * 8);
        #pragma unroll
        for (int i = 0; i < 4; i++)
            #pragma unroll
            for (int j = 0; j < 4; j++)
                acc[i][j] = __builtin_amdgcn_mfma_f32_16x16x32_bf16(af[i], bfg[j], acc[i][j], 0, 0, 0);
    }

    const int of32 = oext & fl;
    const int col_base = bn * 128 + wn * 64;
    const int row_base = bm * 128 + wm * 64;
    #pragma unroll
    for (int j = 0; j < 4; j++) {
        const int col = col_base + j * 16 + ln;
        const float bb = ldsc(bias, col, fl);
        #pragma unroll
        for (int i = 0; i < 4; i++) {
            const int row0 = row_base + i * 16 + quad * 4;
            #pragma unroll
            for (int r = 0; r < 4; r++) {
                const int row = row0 + r;
                float v = acc[i][j][r] + bb;
                if (of32) ((float*)C)[(size_t)row * N + col] = v;
                else      ((ushort*)C)[(size_t)row * N + col] = f2bf(v);
            }
        }
    }
}

// ---------------------------------------------------------------------------
// Persistent LSTM, v3.  64 blocks x 512 threads.  Block jb owns hidden cols
// [jb*16, jb*16+16) for ALL 4 gates; wave = (gate, K-half); W_hh fragment
// (16 x short8 = 64 VGPR) register-resident.  Cross-block h via agent-scope
// atomics (bypass non-coherent caches).  Barrier = 64 distributed flags
// (store-only arrival, no RMW); every wave polls all 64 flags lane-parallel.
__global__ __launch_bounds__(512, 2) void lstm_kernel(
    const ushort* __restrict__ Whhb,   // [4096][1024] bf16
    const ushort* __restrict__ gx,     // [t*32+b][4096] bf16
    const ushort* __restrict__ initb,  // [32][2048] bf16 (h0 | c0)
    ushort* __restrict__ hbuf,         // 2 x [32][1024] bf16 ping-pong (slot0 = h0)
    ushort* __restrict__ hs,           // [b][t][1024] bf16
    unsigned int* __restrict__ flags)  // [64] per-block arrival counters
{
    __shared__ ushort hsm[32 * 1024];          // 64 KB, rows XOR-swizzled
    __shared__ float pbuf[8][32][17];          // partial gates

    const int jb = blockIdx.x;                 // hidden-col block
    const int tid = threadIdx.x;
    const int w = tid >> 6;                    // wave 0..7
    const int lane = tid & 63;
    const int ln = lane & 15, quad = lane >> 4;
    const int s = w >> 1, q = w & 1;           // gate, K-half

    // W_hh fragments -> registers (64 VGPR)
    short8 wf[16];
    {
        const ushort* wb = Whhb + (size_t)(s * 1024 + jb * 16 + ln) * HH + q * 512 + quad * 8;
        #pragma unroll
        for (int kc = 0; kc < 16; kc++)
            wf[kc] = *(const short8*)(wb + kc * 32);
    }

    // cell ownership: thread tid -> (batch cb, hidden col hcol); c in a register
    const int cb = tid >> 4, hc = tid & 15;
    const int hcol = jb * 16 + hc;
    float creg = bf2f(initb[(size_t)cb * 2048 + 1024 + hcol]);

    #pragma unroll 1
    for (int t = 0; t < TT; t++) {
        // gx prefetch (issues before the flag poll; hides under the wait)
        float gxv[4];
        {
            const ushort* gp = gx + ((size_t)t * BB + cb) * 4096 + hcol;
            #pragma unroll
            for (int g = 0; g < 4; g++) gxv[g] = bf2f(gp[g * 1024]);
        }

        // wait until all 64 blocks finished step t-1 (lane l watches flags[l])
        if (t > 0) {
            while (true) {
                unsigned v = __hip_atomic_load(flags + lane, __ATOMIC_RELAXED,
                                               __HIP_MEMORY_SCOPE_AGENT);
                if (__all((int)(v >= (unsigned)t))) break;
            }
            asm volatile("" ::: "memory");     // no hoisting h-loads above the poll
        }

        // cooperative h_t -> LDS via coherent (agent) loads; XOR-swizzle rows
        {
            const ushort* hp = hbuf + (size_t)(t & 1) * BB * HH;
            unsigned long long v[16];
            #pragma unroll
            for (int j = 0; j < 16; j++) {
                const int c = tid + 512 * j;                    // 8B chunk id
                v[j] = __hip_atomic_load((const unsigned long long*)hp + c,
                                         __ATOMIC_RELAXED, __HIP_MEMORY_SCOPE_AGENT);
            }
            #pragma unroll
            for (int j = 0; j < 16; j++) {
                const int c = tid + 512 * j;
                const int row = c >> 8;                         // 2048 B per row
                const int inb = (c & 255) * 8;
                *(unsigned long long*)((char*)hsm + row * 2048 + (inb ^ ((row & 7) << 4))) = v[j];
            }
        }
        __syncthreads();

        // partial gates: (gate s, K-half q) over 32 batches x 16 cols
        floatx4 acc0 = {}, acc1 = {};
        {
            const char* base0 = (const char*)hsm + ln * 2048;
            const char* base1 = (const char*)hsm + (16 + ln) * 2048;
            const int x0 = (ln & 7) << 4, x1 = ((16 + ln) & 7) << 4;
            #pragma unroll
            for (int kc = 0; kc < 16; kc++) {
                const int inb = (q * 512 + kc * 32 + quad * 8) * 2;
                short8 a0 = *(const short8*)(base0 + (inb ^ x0));
                short8 a1 = *(const short8*)(base1 + (inb ^ x1));
                acc0 = __builtin_amdgcn_mfma_f32_16x16x32_bf16(a0, wf[kc], acc0, 0, 0, 0);
                acc1 = __builtin_amdgcn_mfma_f32_16x16x32_bf16(a1, wf[kc], acc1, 0, 0, 0);
            }
        }
        #pragma unroll
        for (int r = 0; r < 4; r++) {
            pbuf[w][quad * 4 + r][ln]      = acc0[r];
            pbuf[w][16 + quad * 4 + r][ln] = acc1[r];
        }
        __syncthreads();

        // cell update: thread owns (cb, hcol)
        {
            float gv[4];
            #pragma unroll
            for (int g = 0; g < 4; g++)
                gv[g] = pbuf[2 * g][cb][hc] + pbuf[2 * g + 1][cb][hc] + gxv[g];
            creg = sigf(gv[1]) * creg + sigf(gv[0]) * tanhf(gv[2]);
            const float hn = sigf(gv[3]) * tanhf(creg);
            unsigned hv = (unsigned)f2bf(hn);
            unsigned up = (unsigned)__shfl_down((int)hv, 1);
            if ((hc & 1) == 0) {                               // paired u32 stores
                const unsigned pk = hv | (up << 16);
                ushort* hnx = hbuf + (size_t)((t + 1) & 1) * BB * HH;
                __hip_atomic_store((unsigned*)(hnx + (size_t)cb * HH + hcol), pk,
                                   __ATOMIC_RELAXED, __HIP_MEMORY_SCOPE_AGENT);
                // hs only read after kernel boundary -> normal (L2) store
                *(unsigned*)(hs + ((size_t)cb * TT + t) * HH + hcol) = pk;
            }
        }

        // release (drain this wave's h stores), then distributed arrival
        __builtin_amdgcn_fence(__ATOMIC_RELEASE, "agent");
        __syncthreads();
        if (tid == 0)
            __hip_atomic_store(flags + jb, (unsigned)(t + 1), __ATOMIC_RELAXED,
                               __HIP_MEMORY_SCOPE_AGENT);
    }
}

// ---------------------------------------------------------------------------
extern "C" void kernel_launch(void* const* d_in, const int* in_sizes, int n_in,
                              void* d_out, int out_size, void* d_ws, size_t ws_size,
                              hipStream_t stream) {
    const char* feats   = (const char*)d_in[0];
    const int*  reports = (const int*) d_in[1];
    const char* fcW     = (const char*)d_in[2];
    const char* fcb     = (const char*)d_in[3];
    const char* emb     = (const char*)d_in[4];
    const char* Wih     = (const char*)d_in[5];
    const char* Whh     = (const char*)d_in[6];
    const char* bih     = (const char*)d_in[7];
    const char* bhh     = (const char*)d_in[8];
    const char* Wv      = (const char*)d_in[9];
    const char* bv      = (const char*)d_in[10];

    // workspace layout (~48.5 MB total), big-first, 16B-aligned
    char* p = (char*)d_ws;
    ushort* gx     = (ushort*)p; p += (size_t)BB * TT * 4096 * 2;     // 32 MB (reused for Wv-bf16 after lstm)
    ushort* hs     = (ushort*)p; p += (size_t)BB * TT * HH * 2;       // 8 MB
    ushort* Whhb   = (ushort*)p; p += (size_t)4096 * HH * 2;          // 8 MB
    ushort* pooled = (ushort*)p; p += (size_t)BB * FF * 2;            // 128 KB
    ushort* initb  = (ushort*)p; p += (size_t)BB * 2048 * 2;          // 128 KB
    ushort* hbuf   = (ushort*)p; p += (size_t)2 * BB * HH * 2;        // 128 KB
    int*    ridx   = (int*)   p; p += (size_t)BB * TT * 4;            // 16 KB
    int*    flag   = (int*)   p; p += 16;
    unsigned int* flags = (unsigned int*)p; p += NBLK * 4;            // 256 B

    detect_kernel<<<1, 64, 0, stream>>>((const ushort*)fcW, flag);
    conv_kernel  <<<16384, 256, 0, stream>>>(Whh, Whhb, 4096 * HH, flag);
    pool_kernel  <<<256, 256, 0, stream>>>(feats, pooled, flag);
    ridx_kernel  <<<16,  256, 0, stream>>>(reports, ridx);

    gemm_bf16<<<dim3(16, 1), 256, 0, stream>>>((const char*)pooled, fcW, nullptr,
                                               fcb, nullptr, (char*)initb,
                                               32, 2048, 2048, flag, 0, 1, 0, 0);
    h0prep_kernel<<<128, 256, 0, stream>>>(initb, hbuf, flags);
    // gates_x = emb[in_idx] @ W_ih^T + (b_ih + b_hh), rows = t*B + b (transposed)
    gemm_bf16<<<dim3(32, 32), 256, 0, stream>>>(emb, Wih, ridx, bih, bhh,
                                                (char*)gx, BB * TT, 4096, EE,
                                                flag, 1, 1, 0, 1);

    {
        const ushort* a0 = Whhb; const ushort* a1 = gx; const ushort* a2 = initb;
        ushort* a3 = hbuf; ushort* a4 = hs; unsigned int* a5 = flags;
        void* kargs[] = { (void*)&a0, (void*)&a1, (void*)&a2,
                          (void*)&a3, (void*)&a4, (void*)&a5 };
        hipLaunchCooperativeKernel(lstm_kernel, dim3(NBLK), dim3(512), kargs, 0, stream);
    }

    // gx is dead now: convert Wv -> bf16 into it, then fast all-bf16 final GEMM
    ushort* Wvb = gx;                                  // 16000*1024*2 = 32.8 MB <= gx region
    conv_kernel<<<64000, 256, 0, stream>>>(Wv, Wvb, VV * HH, flag);
    gemm_bf16_fast<<<dim3(32, 125), 256, 0, stream>>>((const ushort*)hs, Wvb,
                                                      bv, (char*)d_out,
                                                      BB * TT, VV, HH, flag,
                                                      1, 32, 125);
}